// Round 9
// baseline (13872.156 us; speedup 1.0000x reference)
//
#include <hip/hip_runtime.h>
#include <math.h>

#define NB   128   // batch
#define SEQ  512   // sequence length
#define HD   128   // hidden
#define NCL  16    // clusters C
#define NOUT 8     // classes
#define CIP  272   // ci padded (260 real)
#define FEPS 1e-4f
#define HP   132   // padded row stride (uniform bank spread; 132%32=4)
#define W1P  132   // s_w1 row stride, same reason; 16B-aligned (528B)

// NOTE: macro param must NOT be named 'w'/'x'/'y'/'z' (member-access collision).
#define FMA4(cc, W4) { a0 = fmaf((cc),(W4).x,a0); a1 = fmaf((cc),(W4).y,a1); a2 = fmaf((cc),(W4).z,a2); a3 = fmaf((cc),(W4).w,a3); }
#define XOR4(msk) { a0 += __shfl_xor(a0,msk); a1 += __shfl_xor(a1,msk); a2 += __shfl_xor(a2,msk); a3 += __shfl_xor(a3,msk); }

__device__ __forceinline__ float red16(float v){
    v += __shfl_xor(v, 1, 16); v += __shfl_xor(v, 2, 16);
    v += __shfl_xor(v, 4, 16); v += __shfl_xor(v, 8, 16);
    return v;
}
__device__ __forceinline__ float max16(float v){
    v = fmaxf(v, __shfl_xor(v, 1, 16)); v = fmaxf(v, __shfl_xor(v, 2, 16));
    v = fmaxf(v, __shfl_xor(v, 4, 16)); v = fmaxf(v, __shfl_xor(v, 8, 16));
    return v;
}
__device__ __forceinline__ float red64(float v){
    v += __shfl_xor(v, 1, 64); v += __shfl_xor(v, 2, 64); v += __shfl_xor(v, 4, 64);
    v += __shfl_xor(v, 8, 64); v += __shfl_xor(v,16, 64); v += __shfl_xor(v,32, 64);
    return v;
}
__device__ __forceinline__ float sigm(float x){ return 1.f/(1.f + expf(-x)); }
__device__ __forceinline__ float softplusf(float x){ return log1pf(expf(-fabsf(x))) + fmaxf(x, 0.f); }

// 512 threads (R6 shape — R8's 1024-thread test was confounded: VGPR halved to
// 64 + self-inflicted gram bank conflicts). This round: 12 -> 8 barriers via
// j-ownership in-wave shfl reductions; summarize moved to prev-step tail;
// diversity via d = (sum_c a_c|c_c|^2 - |core|^2)/128.
// Register discipline (R4/R5): no persistent per-thread arrays.
__global__ __launch_bounds__(512)
void cfrm_kernel(const int*  __restrict__ tokens,
                 const float* __restrict__ emb,
                 const float* __restrict__ ln_g, const float* __restrict__ ln_b,
                 const float* __restrict__ w1,   const float* __restrict__ b1,
                 const float* __restrict__ w2,   const float* __restrict__ b2,
                 const float* __restrict__ gate_w, const float* __restrict__ gate_b,
                 const float* __restrict__ assign_w, const float* __restrict__ assign_b,
                 const float* __restrict__ nov_w, const float* __restrict__ nov_b,
                 const float* __restrict__ relax_w, const float* __restrict__ relax_b,
                 const float* __restrict__ cc_w, const float* __restrict__ cc_b,
                 const float* __restrict__ cs_w, const float* __restrict__ cs_b,
                 const float* __restrict__ md_w, const float* __restrict__ md_b,
                 const float* __restrict__ att_w, const float* __restrict__ att_b,
                 const float* __restrict__ cw1,  const float* __restrict__ cb1,
                 const float* __restrict__ cw2,  const float* __restrict__ cb2,
                 float* __restrict__ out)
{
    const int bidx = blockIdx.x;
    const int tid  = threadIdx.x;
    const int lane = tid & 63;
    const int wv   = tid >> 6;          // 0..7

    // ---- LDS (~150 KiB; 1 block/CU) ----
    __shared__ __align__(16) float s_w1[260][W1P];  // 137.3 KB, staged once
    __shared__ __align__(16) float s_centers[NCL][HP];
    __shared__ __align__(16) float s_ci[CIP];       // [token|core|u,d,en,ent|pad]
    __shared__ __align__(16) float s_ctrl1[HD];
    __shared__ __align__(16) float s_ctrl[HD];
    __shared__ __align__(16) float s_att[HD];
    __shared__ __align__(16) float s_gram[NCL][NCL+1];
    __shared__ __align__(16) float s_mix[NCL][NCL+1];
    __shared__ __align__(16) float s_alpha[NCL];
    __shared__ float s_spreads[NCL], s_masses[NCL];
    __shared__ __align__(16) float s_ss[NCL];
    __shared__ __align__(16) float s_cands[NCL];
    __shared__ __align__(16) float s_mdl[NCL];
    __shared__ float s_ms[NCL], s_mm[NCL];
    __shared__ float s_scal[2];
    __shared__ float s_csq[2];          // |core|^2 partials (waves 1,2)
    __shared__ float s_dm2;             // sum_c alpha_c |c_c|^2 / 128
    __shared__ int   s_ibest;
    __shared__ int   s_tok[SEQ];

    // ---- stage w1 -> LDS (one-time; 260 rows x 32 float4, stride 33 f4) ----
    {
        const float4* w1f4 = (const float4*)w1;
        for (int idx = tid; idx < 260*32; idx += 512){
            int k = idx >> 5, q = idx & 31;
            *((float4*)&s_w1[k][0] + q) = w1f4[idx];
        }
    }

    // ---- init state / token preload ----
    for (int i = tid; i < NCL*HP; i += 512) ((float*)s_centers)[i] = 0.f;
    if (tid >= 260 && tid < CIP) s_ci[tid] = 0.f;
    s_tok[tid] = tokens[bidx*SEQ + tid];

    // ---- per-thread constant preloads ----
    const int jq = tid >> 4, pp = tid & 15;      // w1/w2 j-own mapping
    float4 rb1q = {0,0,0,0}, rw257q = {0,0,0,0}, rb2q = {0,0,0,0};
    if (pp == 0){
        rb1q   = *(const float4*)(b1 + jq*4);
        rw257q = *(const float4*)(w1 + 257*HD + jq*4);
        rb2q   = *(const float4*)(b2 + jq*4);
    }
    const int ja = tid >> 3, pa = tid & 7;       // att mapping (tid<256)
    float4 rattq = {0,0,0,0};
    if (tid < 256 && pa == 0) rattq = *(const float4*)(att_b + ja*4);
    // heads (waves 4,5): lane = c4*16 + ph
    const int c4 = lane >> 4, ph = lane & 15;
    float4 hbAq = {0,0,0,0}, hbBq = {0,0,0,0};
    if (wv == 4 && ph == 0){ hbAq = *(const float4*)(gate_b + c4*4); hbBq = *(const float4*)(assign_b + c4*4); }
    if (wv == 5 && ph == 0){ hbAq = *(const float4*)(cs_b + c4*4);   hbBq = *(const float4*)(md_b + c4*4); }
    // nov/relax (wave 6): which = lane>>5, kq6 = lane&31
    const int which6 = lane >> 5, kq6 = lane & 31;
    float4 nr4 = {0,0,0,0}; float nrb = 0.f;
    if (wv == 6){
        const float* nbase = which6 ? relax_w : nov_w;
        nr4 = *(const float4*)(nbase + kq6*4);
        nrb = which6 ? relax_b[0] : nov_b[0];
    }
    float rg0=0.f, rg1=0.f, rlb0=0.f, rlb1=0.f;
    if (wv == 0){ rg0 = ln_g[lane]; rg1 = ln_g[64+lane]; rlb0 = ln_b[lane]; rlb1 = ln_b[64+lane]; }

    // phase-7 geometry (unchanged from R6)
    const int j0 = tid*4, ci_c = j0 >> 7, ci_h = j0 & 127;
    const float4 ccb4 = *(const float4*)(cc_b + j0);
    const float* wp = cc_w + j0;

    // ---- initial summarize (state: sp=1, ma=0) ----
    if (tid < NCL){
        s_spreads[tid] = 1.f; s_masses[tid] = 0.f;
        float sp = 1.f, ma = 0.f;
        float prec = 1.f/(sp + FEPS);
        float sc = ma + logf(prec + FEPS);
        float mx = max16(sc);
        float ex = expf(sc - mx);
        float smn = red16(ex);
        float al = ex / smn;
        s_alpha[tid] = al;
        float u = red16(al * sp);
        float mmx = max16(ma);
        float es = red16(expf(ma - mmx));
        float ent = -red16(al * logf(fmaxf(al, 1e-8f)));
        if (tid == 0){ s_ci[256] = u; s_ci[258] = mmx + logf(es); s_ci[259] = ent; }
    }
    __syncthreads();

    // emb prefetch for s=0
    float e0c = 0.f, e1c = 0.f;
    if (wv == 0){
        int t0 = s_tok[0];
        e0c = emb[(size_t)t0*HD + lane];
        e1c = emb[(size_t)t0*HD + 64 + lane];
    }

    for (int s = 0; s < SEQ; ++s){
        const int tok = s_tok[s];
        const float valid = (tok != 0) ? 1.f : 0.f;

        float e0n = 0.f, e1n = 0.f;
        if (wv == 0 && s + 1 < SEQ){
            int tn = s_tok[s+1];
            e0n = emb[(size_t)tn*HD + lane];
            e1n = emb[(size_t)tn*HD + 64 + lane];
        }

        // ==== Ph1: LN(wv0) | core+|core|^2 (wv1-2) | alpha*m2 (wv3) ====
        if (wv == 0){
            float sm = red64(e0c + e1c);
            float sq = red64(e0c*e0c + e1c*e1c);
            float mu  = sm * (1.f/128.f);
            float var = sq * (1.f/128.f) - mu*mu;
            float inv = 1.f / sqrtf(var + 1e-5f);
            s_ci[lane]      = (e0c - mu)*inv*rg0 + rlb0;
            s_ci[64 + lane] = (e1c - mu)*inv*rg1 + rlb1;
        } else if (wv == 1 || wv == 2){
            int t = tid - 64;                     // 0..127
            float acc = 0.f;
            #pragma unroll
            for (int c = 0; c < NCL; ++c) acc += s_alpha[c] * s_centers[c][t];
            s_ci[128 + t] = acc;
            float cs = red64(acc * acc);
            if (lane == 0) s_csq[wv - 1] = cs;
        } else if (wv == 3){
            int c = lane >> 2, p4 = lane & 3;
            float acc = 0.f;
            #pragma unroll 8
            for (int hh = p4*32; hh < p4*32 + 32; ++hh){
                float cv = s_centers[c][hh];
                acc = fmaf(cv, cv, acc);
            }
            acc += __shfl_xor(acc, 1, 4); acc += __shfl_xor(acc, 2, 4);
            float v = (p4 == 0) ? s_alpha[c]*acc*(1.f/128.f) : 0.f;
            v = red64(v);
            if (lane == 0) s_dm2 = v;
        }
        __syncthreads();  // B1

        // ==== Ph2: ctrl1 = tanh(ci @ w1 + b1), j-own, in-wave reduce ====
        {
            float a0=0.f,a1=0.f,a2=0.f,a3=0.f;
            #pragma unroll
            for (int u = 0; u < 17; ++u){
                int k = pp*17 + u;
                int kc = (k < 260) ? k : 0;
                float cv = (k == 257 || k >= 260) ? 0.f : s_ci[k];
                float4 w4 = *((const float4*)&s_w1[kc][0] + jq);
                FMA4(cv, w4)
            }
            XOR4(1) XOR4(2) XOR4(4) XOR4(8)
            if (pp == 0){
                float d = s_dm2 - (s_csq[0] + s_csq[1]) * (1.f/128.f);
                a0 += rb1q.x + rw257q.x * d;
                a1 += rb1q.y + rw257q.y * d;
                a2 += rb1q.z + rw257q.z * d;
                a3 += rb1q.w + rw257q.w * d;
                *(float4*)&s_ctrl1[jq*4] = make_float4(tanhf(a0), tanhf(a1), tanhf(a2), tanhf(a3));
            }
        }
        __syncthreads();  // B2

        // ==== Ph3: ctrl = tanh(ctrl1 @ w2 + b2), j-own ====
        {
            float a0=0.f,a1=0.f,a2=0.f,a3=0.f;
            #pragma unroll
            for (int u = 0; u < 8; ++u){
                int k = pp*8 + u;
                float4 w4 = *(const float4*)(w2 + k*HD + jq*4);
                float cl = s_ctrl1[k];
                FMA4(cl, w4)
            }
            XOR4(1) XOR4(2) XOR4(4) XOR4(8)
            if (pp == 0){
                a0 += rb2q.x; a1 += rb2q.y; a2 += rb2q.z; a3 += rb2q.w;
                *(float4*)&s_ctrl[jq*4] = make_float4(tanhf(a0), tanhf(a1), tanhf(a2), tanhf(a3));
            }
        }
        __syncthreads();  // B3

        // ==== Ph4: att (wv0-3) | gate+assign->ss (wv4) | cs+md (wv5) | nov/relax (wv6) ====
        if (wv < 4){
            float a0=0.f,a1=0.f,a2=0.f,a3=0.f;
            #pragma unroll
            for (int u = 0; u < 16; ++u){
                int k = pa*16 + u;
                float4 w4 = *(const float4*)(att_w + k*HD + ja*4);
                float cl = s_ctrl[k];
                FMA4(cl, w4)
            }
            XOR4(1) XOR4(2) XOR4(4)
            if (pa == 0){
                *(float4*)&s_att[ja*4] = make_float4(a0 + rattq.x, a1 + rattq.y, a2 + rattq.z, a3 + rattq.w);
            }
        } else if (wv == 4){
            // pass A: gate
            float a0=0.f,a1=0.f,a2=0.f,a3=0.f;
            #pragma unroll
            for (int u = 0; u < 8; ++u){
                int k = ph*8 + u;
                float4 w4 = *(const float4*)(gate_w + k*NCL + c4*4);
                float cl = s_ctrl[k];
                FMA4(cl, w4)
            }
            XOR4(1) XOR4(2) XOR4(4) XOR4(8)
            float g0=0.f,g1=0.f,g2=0.f,g3=0.f;
            if (ph == 0){
                g0 = sigm(a0 + hbAq.x)*valid; g1 = sigm(a1 + hbAq.y)*valid;
                g2 = sigm(a2 + hbAq.z)*valid; g3 = sigm(a3 + hbAq.w)*valid;
            }
            // pass B: assign (softmax over 16 c at ph==0 lanes 0,16,32,48)
            a0=0.f;a1=0.f;a2=0.f;a3=0.f;
            #pragma unroll
            for (int u = 0; u < 8; ++u){
                int k = ph*8 + u;
                float4 w4 = *(const float4*)(assign_w + k*NCL + c4*4);
                float cl = s_ctrl[k];
                FMA4(cl, w4)
            }
            XOR4(1) XOR4(2) XOR4(4) XOR4(8)
            a0 += hbBq.x; a1 += hbBq.y; a2 += hbBq.z; a3 += hbBq.w;
            float mx = fmaxf(fmaxf(a0,a1), fmaxf(a2,a3));
            mx = fmaxf(mx, __shfl_xor(mx,16)); mx = fmaxf(mx, __shfl_xor(mx,32));
            float e0 = expf(a0-mx), e1 = expf(a1-mx), e2 = expf(a2-mx), e3 = expf(a3-mx);
            float sm = e0+e1+e2+e3;
            sm += __shfl_xor(sm,16); sm += __shfl_xor(sm,32);
            if (ph == 0){
                float inv = 1.f/sm;
                *(float4*)&s_ss[c4*4] = make_float4(g0*e0*inv, g1*e1*inv, g2*e2*inv, g3*e3*inv);
            }
        } else if (wv == 5){
            // pass A: cs
            float a0=0.f,a1=0.f,a2=0.f,a3=0.f;
            #pragma unroll
            for (int u = 0; u < 8; ++u){
                int k = ph*8 + u;
                float4 w4 = *(const float4*)(cs_w + k*NCL + c4*4);
                float cl = s_ctrl[k];
                FMA4(cl, w4)
            }
            XOR4(1) XOR4(2) XOR4(4) XOR4(8)
            if (ph == 0){
                *(float4*)&s_cands[c4*4] = make_float4(
                    softplusf(a0 + hbAq.x) + FEPS, softplusf(a1 + hbAq.y) + FEPS,
                    softplusf(a2 + hbAq.z) + FEPS, softplusf(a3 + hbAq.w) + FEPS);
            }
            // pass B: md
            a0=0.f;a1=0.f;a2=0.f;a3=0.f;
            #pragma unroll
            for (int u = 0; u < 8; ++u){
                int k = ph*8 + u;
                float4 w4 = *(const float4*)(md_w + k*NCL + c4*4);
                float cl = s_ctrl[k];
                FMA4(cl, w4)
            }
            XOR4(1) XOR4(2) XOR4(4) XOR4(8)
            if (ph == 0){
                *(float4*)&s_mdl[c4*4] = make_float4(
                    tanhf(a0 + hbBq.x), tanhf(a1 + hbBq.y), tanhf(a2 + hbBq.z), tanhf(a3 + hbBq.w));
            }
        } else if (wv == 6){
            float4 cv = *(const float4*)&s_ctrl[kq6*4];
            float acc = cv.x*nr4.x + cv.y*nr4.y + cv.z*nr4.z + cv.w*nr4.w;
            acc += __shfl_xor(acc, 1, 32); acc += __shfl_xor(acc, 2, 32);
            acc += __shfl_xor(acc, 4, 32); acc += __shfl_xor(acc, 8, 32);
            acc += __shfl_xor(acc,16, 32);
            if (kq6 == 0) s_scal[which6] = sigm(acc + nrb) * valid;
        }
        __syncthreads();  // B4

        // ==== Ph5: cand centers stream + center/spread/mass update (R6) ====
        {
            float a0=0.f,a1=0.f,a2=0.f,a3=0.f;
            #pragma unroll 16
            for (int k = 0; k < HD; ++k){
                float cl = s_ctrl[k];
                float4 w4 = *(const float4*)(wp + (k << 11));
                FMA4(cl, w4)
            }
            float ssc = s_ss[ci_c];
            float nv  = s_scal[0];
            float4 av = *(const float4*)&s_att[ci_h];
            float4* cp = (float4*)&s_centers[ci_c][ci_h];
            float4 ov = *cp;
            float x0 = ov.x + ssc*((a0 + ccb4.x) - ov.x); x0 = fmaf(0.1f*nv, av.x - x0, x0);
            float x1 = ov.y + ssc*((a1 + ccb4.y) - ov.y); x1 = fmaf(0.1f*nv, av.y - x1, x1);
            float x2 = ov.z + ssc*((a2 + ccb4.z) - ov.z); x2 = fmaf(0.1f*nv, av.z - x2, x2);
            float x3 = ov.w + ssc*((a3 + ccb4.w) - ov.w); x3 = fmaf(0.1f*nv, av.w - x3, x3);
            *cp = make_float4(x0, x1, x2, x3);
        }
        if (tid < NCL){
            float ssc = s_ss[tid];
            s_spreads[tid] += ssc * (s_cands[tid] - s_spreads[tid]);
            s_masses[tid]  += ssc * s_mdl[tid];
        }
        __syncthreads();  // B5

        // ==== Ph6: gram (R6 mapping — no k-split, conflict-free at HP=132) ====
        if (tid < 256){
            int gi = tid >> 4, gj = tid & 15;
            const float4* ri = (const float4*)&s_centers[gi][0];
            const float4* rj = (const float4*)&s_centers[gj][0];
            float acc = 0.f;
            #pragma unroll 8
            for (int h4 = 0; h4 < 32; ++h4){
                float4 a = ri[h4], b = rj[h4];
                acc = fmaf(a.x,b.x,fmaf(a.y,b.y,fmaf(a.z,b.z,fmaf(a.w,b.w,acc))));
            }
            s_gram[gi][gj] = acc;
        }
        __syncthreads();  // B6

        // ==== Ph7: mixing softmax + mixed spreads/masses ====
        if (tid < 256){
            int i = tid >> 4, jx = tid & 15;
            float g  = s_gram[i][jx];
            float d2 = fmaxf(s_gram[i][i] + s_gram[jx][jx] - 2.f*g, 0.f);
            float scale = s_spreads[i] + s_spreads[jx] + FEPS;
            float cmp = -d2/scale + s_masses[jx];
            float mx = max16(cmp);
            float ex = expf(cmp - mx);
            float smn = red16(ex);
            float mix = ex / smn;
            s_mix[i][jx] = mix;
            float msp = red16(mix * s_spreads[jx]);
            float mma = red16(mix * s_masses[jx]);
            if (jx == 0){ s_ms[i] = msp; s_mm[i] = mma; }
        }
        __syncthreads();  // B7

        // ==== Ph8: mixed centers + relax blend (R6 quarter-wave-safe) +
        //          shrink + NEXT-step summarize (tid<16) ====
        {
            int i = tid & 15, hh = (tid >> 4)*4;
            float a0=0.f,a1=0.f,a2=0.f,a3=0.f;
            #pragma unroll
            for (int jc = 0; jc < NCL; ++jc){
                float m = s_mix[i][jc];
                float4 cv = *(const float4*)&s_centers[jc][hh];
                a0 = fmaf(m, cv.x, a0); a1 = fmaf(m, cv.y, a1);
                a2 = fmaf(m, cv.z, a2); a3 = fmaf(m, cv.w, a3);
            }
            float rx = s_scal[1];
            float4* cp2 = (float4*)&s_centers[i][hh];
            float4 ov = *cp2;
            ov.x = (1.f - rx)*ov.x + rx*a0;
            ov.y = (1.f - rx)*ov.y + rx*a1;
            ov.z = (1.f - rx)*ov.z + rx*a2;
            ov.w = (1.f - rx)*ov.w + rx*a3;
            *cp2 = ov;
        }
        if (tid < NCL){
            float rx = s_scal[1];
            float sp = (1.f - rx)*s_spreads[tid] + rx*s_ms[tid];
            float ma = (1.f - rx)*s_masses[tid]  + rx*s_mm[tid];
            float prec = 1.f/(sp + FEPS);
            float sc = ma + logf(prec + FEPS);
            float mx = max16(sc);
            float ex = expf(sc - mx);
            float smn = red16(ex);
            float ca = ex / smn;
            sp = sp*(1.f - 0.05f*ca*valid) + FEPS;
            s_spreads[tid] = sp;
            s_masses[tid]  = ma;
            // next-step summarize (post-shrink state)
            float prec2 = 1.f/(sp + FEPS);
            float sc2 = ma + logf(prec2 + FEPS);
            float mx2 = max16(sc2);
            float ex2 = expf(sc2 - mx2);
            float sm2 = red16(ex2);
            float al = ex2 / sm2;
            s_alpha[tid] = al;
            float u = red16(al * sp);
            float mmx = max16(ma);
            float es = red16(expf(ma - mmx));
            float ent = -red16(al * logf(fmaxf(al, 1e-8f)));
            if (tid == 0){ s_ci[256] = u; s_ci[258] = mmx + logf(es); s_ci[259] = ent; }
        }
        e0c = e0n; e1c = e1n;
        __syncthreads();  // B8
    }

    // ================= epilogue =================
    // s_alpha / s_ci[256,258,259] already hold the final summarize (Ph8 tail).
    if (tid < HD){
        float acc = 0.f;
        #pragma unroll
        for (int c = 0; c < NCL; ++c) acc += s_alpha[c] * s_centers[c][tid];
        s_ci[tid] = acc;   // core -> feats[0:128]
    }
    __syncthreads();
    if (wv == 0){
        int c = lane >> 2, p = lane & 3;
        float acc = 0.f;
        #pragma unroll 8
        for (int hh = p*32; hh < p*32 + 32; ++hh){
            float d = s_centers[c][hh] - s_ci[hh];
            acc += d*d;
        }
        acc += __shfl_xor(acc, 1, 4); acc += __shfl_xor(acc, 2, 4);
        float v = ((lane & 3) == 0) ? s_alpha[c]*acc*(1.f/128.f) : 0.f;
        v = red64(v);
        if (lane == 0) s_ci[257] = v;
    }
    if (wv == 1 && lane == 0){
        int best = 0; float bv = s_alpha[0];
        for (int c = 1; c < NCL; ++c){ if (s_alpha[c] > bv){ bv = s_alpha[c]; best = c; } }
        s_ibest = best;
    }
    __syncthreads();
    if (tid < HD) s_ci[128 + tid] = s_centers[s_ibest][tid];   // strongest
    __syncthreads();
    // classifier layer 1 (one-time); s_w1 rows 0-3 reused as partial scratch
    {
        int j = tid & 127, p4 = tid >> 7;
        int k0 = p4*65;
        float acc = 0.f;
        for (int k = k0; k < k0 + 65; ++k) acc += s_ci[k] * cw1[k*HD + j];
        s_w1[p4][j] = acc;
    }
    __syncthreads();
    if (tid < HD){
        float x = cb1[tid] + s_w1[0][tid] + s_w1[1][tid] + s_w1[2][tid] + s_w1[3][tid];
        s_ctrl1[tid] = 0.5f*x*(1.f + erff(x*0.70710678118654752f));  // exact gelu
    }
    __syncthreads();
    // classifier layer 2 -> out
    if (tid < 64){
        int n = tid >> 3, p = tid & 7;
        float acc = 0.f;
        #pragma unroll
        for (int kk = 0; kk < 16; ++kk){ int jx = p*16 + kk; acc += s_ctrl1[jx] * cw2[jx*NOUT + n]; }
        acc += __shfl_xor(acc, 1, 8); acc += __shfl_xor(acc, 2, 8); acc += __shfl_xor(acc, 4, 8);
        if (p == 0) out[bidx*NOUT + n] = acc + cb2[n];
    }
}

extern "C" void kernel_launch(void* const* d_in, const int* in_sizes, int n_in,
                              void* d_out, int out_size, void* d_ws, size_t ws_size,
                              hipStream_t stream) {
    const int*   tokens   = (const int*)  d_in[0];
    const float* emb      = (const float*)d_in[1];
    const float* ln_g     = (const float*)d_in[2];
    const float* ln_b     = (const float*)d_in[3];
    const float* ctrl_w1  = (const float*)d_in[4];
    const float* ctrl_b1  = (const float*)d_in[5];
    const float* ctrl_w2  = (const float*)d_in[6];
    const float* ctrl_b2  = (const float*)d_in[7];
    const float* gate_w   = (const float*)d_in[8];
    const float* gate_b   = (const float*)d_in[9];
    const float* assign_w = (const float*)d_in[10];
    const float* assign_b = (const float*)d_in[11];
    const float* nov_w    = (const float*)d_in[12];
    const float* nov_b    = (const float*)d_in[13];
    const float* relax_w  = (const float*)d_in[14];
    const float* relax_b  = (const float*)d_in[15];
    const float* cc_w     = (const float*)d_in[16];
    const float* cc_b     = (const float*)d_in[17];
    const float* cs_w     = (const float*)d_in[18];
    const float* cs_b     = (const float*)d_in[19];
    const float* md_w     = (const float*)d_in[20];
    const float* md_b     = (const float*)d_in[21];
    const float* att_w    = (const float*)d_in[22];
    const float* att_b    = (const float*)d_in[23];
    const float* cls_w1   = (const float*)d_in[24];
    const float* cls_b1   = (const float*)d_in[25];
    const float* cls_w2   = (const float*)d_in[26];
    const float* cls_b2   = (const float*)d_in[27];
    float* out = (float*)d_out;

    hipLaunchKernelGGL(cfrm_kernel, dim3(NB), dim3(512), 0, stream,
                       tokens, emb, ln_g, ln_b,
                       ctrl_w1, ctrl_b1, ctrl_w2, ctrl_b2,
                       gate_w, gate_b, assign_w, assign_b,
                       nov_w, nov_b, relax_w, relax_b,
                       cc_w, cc_b, cs_w, cs_b, md_w, md_b,
                       att_w, att_b, cls_w1, cls_b1, cls_w2, cls_b2,
                       out);
}

// Round 10
// 12675.475 us; speedup vs baseline: 1.0944x; 1.0944x over previous
//
#include <hip/hip_runtime.h>
#include <math.h>

#define NB   128   // batch
#define SEQ  512   // sequence length
#define HD   128   // hidden
#define NCL  16    // clusters C
#define NOUT 8     // classes
#define CIP  288   // ci padded (260 real; 32x9 k-split reads up to 287)
#define FEPS 1e-4f
#define HP   132   // padded row stride for centers

// NOTE: macro param must NOT be named 'w'/'x'/'y'/'z' (member-access collision).
#define FMA4(cc, W4) { a0 = fmaf((cc),(W4).x,a0); a1 = fmaf((cc),(W4).y,a1); a2 = fmaf((cc),(W4).z,a2); a3 = fmaf((cc),(W4).w,a3); }
#define XOR4W(msk) { a0 += __shfl_xor(a0,msk); a1 += __shfl_xor(a1,msk); a2 += __shfl_xor(a2,msk); a3 += __shfl_xor(a3,msk); }

__device__ __forceinline__ float red16(float v){
    v += __shfl_xor(v, 1, 16); v += __shfl_xor(v, 2, 16);
    v += __shfl_xor(v, 4, 16); v += __shfl_xor(v, 8, 16);
    return v;
}
__device__ __forceinline__ float max16(float v){
    v = fmaxf(v, __shfl_xor(v, 1, 16)); v = fmaxf(v, __shfl_xor(v, 2, 16));
    v = fmaxf(v, __shfl_xor(v, 4, 16)); v = fmaxf(v, __shfl_xor(v, 8, 16));
    return v;
}
__device__ __forceinline__ float red64(float v){
    v += __shfl_xor(v, 1, 64); v += __shfl_xor(v, 2, 64); v += __shfl_xor(v, 4, 64);
    v += __shfl_xor(v, 8, 64); v += __shfl_xor(v,16, 64); v += __shfl_xor(v,32, 64);
    return v;
}
__device__ __forceinline__ float sigm(float x){ return 1.f/(1.f + expf(-x)); }
__device__ __forceinline__ float softplusf(float x){ return log1pf(expf(-fabsf(x))) + fmaxf(x, 0.f); }

// Clean TLP retest: 1024 threads (16 waves = 4/SIMD; LDS caps at 1 block/CU).
// R8's confounds removed: R6-exact layouts for gram/mix/att/heads; k-splits
// use in-wave xor-32 (w1/w2) with R6's contiguous jj reads, and cc_w splits k
// into CONTIGUOUS halves (k = kh*64+i) preserving 512B runs per wave-instr.
// R9 lesson: j-own strided layouts = bank conflicts + L2 request bloat. Keep
// weight reads contiguous per wave. R4/R5: no persistent per-thread arrays.
__global__ __launch_bounds__(1024) __attribute__((amdgpu_waves_per_eu(4, 4)))
void cfrm_kernel(const int*  __restrict__ tokens,
                 const float* __restrict__ emb,
                 const float* __restrict__ ln_g, const float* __restrict__ ln_b,
                 const float* __restrict__ w1,   const float* __restrict__ b1,
                 const float* __restrict__ w2,   const float* __restrict__ b2,
                 const float* __restrict__ gate_w, const float* __restrict__ gate_b,
                 const float* __restrict__ assign_w, const float* __restrict__ assign_b,
                 const float* __restrict__ nov_w, const float* __restrict__ nov_b,
                 const float* __restrict__ relax_w, const float* __restrict__ relax_b,
                 const float* __restrict__ cc_w, const float* __restrict__ cc_b,
                 const float* __restrict__ cs_w, const float* __restrict__ cs_b,
                 const float* __restrict__ md_w, const float* __restrict__ md_b,
                 const float* __restrict__ att_w, const float* __restrict__ att_b,
                 const float* __restrict__ cw1,  const float* __restrict__ cb1,
                 const float* __restrict__ cw2,  const float* __restrict__ cb2,
                 float* __restrict__ out)
{
    const int bidx = blockIdx.x;
    const int tid  = threadIdx.x;
    const int lane = tid & 63;
    const int wv   = tid >> 6;          // 0..15

    // ---- LDS (~154 KiB; 1 block/CU) ----
    __shared__ __align__(16) float s_w1[260][HD];   // 133.1 KB, staged once
    __shared__ __align__(16) float s_centers[NCL][HP];
    __shared__ __align__(16) float s_ci[CIP];       // [token|core|u,d,en,ent|pad=0]
    __shared__ __align__(16) float s_ctrl1[HD];
    __shared__ __align__(16) float s_ctrl[HD];
    __shared__ __align__(16) float s_red16[16][HD]; // w1/w2 partials; rows 0-7 reused for att
    __shared__ __align__(16) float s_hred[4][NCL];
    __shared__ __align__(16) float s_att[HD];
    __shared__ __align__(16) float s_gram[NCL][NCL+1];
    __shared__ __align__(16) float s_mix[NCL][NCL+1];
    __shared__ float s_alpha[NCL], s_spreads[NCL], s_masses[NCL];
    __shared__ float s_ss[NCL], s_cands[NCL], s_mdl[NCL];
    __shared__ float s_ms[NCL], s_mm[NCL];
    __shared__ float s_scal[2];
    __shared__ int   s_ibest;
    __shared__ int   s_tok[SEQ];

    // ---- stage w1 -> LDS (one-time; 8320 float4) ----
    {
        const float4* w1f4 = (const float4*)w1;
        float4* s_w1f4 = (float4*)s_w1;
        for (int idx = tid; idx < 260*32; idx += 1024) s_w1f4[idx] = w1f4[idx];
    }

    // ---- init state / token preload ----
    for (int i = tid; i < NCL*HP; i += 1024) ((float*)s_centers)[i] = 0.f;
    if (tid >= 260 && tid < CIP) s_ci[tid] = 0.f;
    if (tid < NCL){ s_spreads[tid] = 1.f; s_masses[tid] = 0.f; }
    if (tid < SEQ) s_tok[tid] = tokens[bidx*SEQ + tid];

    // ---- per-thread constant preloads (scalars only) ----
    float rb1 = 0.f, rb2 = 0.f, ratt = 0.f, rw257 = 0.f;
    if (tid < HD){ rb1 = b1[tid]; rb2 = b2[tid]; ratt = att_b[tid]; rw257 = w1[257*HD + tid]; }
    float rg0=0.f, rg1=0.f, rlb0=0.f, rlb1=0.f;
    if (wv == 0){ rg0 = ln_g[lane]; rg1 = ln_g[64+lane]; rlb0 = ln_b[lane]; rlb1 = ln_b[64+lane]; }
    float rgb=0.f, rab=0.f, rcb=0.f, rmb=0.f;
    if (wv == 2 && lane < NCL){ rgb = gate_b[lane]; rab = assign_b[lane]; rcb = cs_b[lane]; rmb = md_b[lane]; }
    float rnw0=0.f, rnw1=0.f, rrw0=0.f, rrw1=0.f, rnb=0.f, rrb=0.f;
    if (wv == 3){ rnw0 = nov_w[lane]; rnw1 = nov_w[64+lane]; rrw0 = relax_w[lane]; rrw1 = relax_w[64+lane];
                  rnb = nov_b[0]; rrb = relax_b[0]; }

    // phase-7 geometry: quad q = tid>>1, k-half CONTIGUOUS (kh*64 + i)
    const int q7 = tid >> 1, kh7 = tid & 1;
    const int c7 = q7 >> 5, h7 = (q7 & 31) * 4;
    const float* wq7 = cc_w + q7*4;
    const float4 ccb4 = *(const float4*)(cc_b + q7*4);

    // matvec mappings (w1: 32 parts x 9; w2: 32 parts x 4; contiguous jj reads)
    const int jj    = (lane & 31) * 4;
    const int part  = tid >> 5;             // 0..31; parts 2w,2w+1 live in wave w
    const int k0w1  = part*9;               // 32x9 = 288 covers 260 (guarded)
    const int k0w2  = part*4;               // 32x4 = 128 exact

    // att/heads geometry (R6-exact; tids 0-511 only)
    const int parta = (tid >> 5) & 7;       // att: tid<256 -> 0..7
    const int k0a   = parta*16;
    const float* hwp = gate_w; int c4i = 0, k0h = 0;
    if (wv >= 4 && wv < 8){
        int head = wv - 4;
        hwp = (head==0) ? gate_w : (head==1) ? assign_w : (head==2) ? cs_w : md_w;
        c4i = lane & 3; k0h = (lane >> 2)*8;
    }

    __syncthreads();

    // emb prefetch for s=0
    float e0c = 0.f, e1c = 0.f;
    if (wv == 0){
        int t0 = s_tok[0];
        e0c = emb[(size_t)t0*HD + lane];
        e1c = emb[(size_t)t0*HD + 64 + lane];
    }

    for (int s = 0; s < SEQ; ++s){
        const int tok = s_tok[s];
        const float valid = (tok != 0) ? 1.f : 0.f;

        float e0n = 0.f, e1n = 0.f;
        if (wv == 0 && s + 1 < SEQ){
            int tn = s_tok[s+1];
            e0n = emb[(size_t)tn*HD + lane];
            e1n = emb[(size_t)tn*HD + 64 + lane];
        }

        // ---- phase 1: LayerNorm (wv0) | summarize (wv1 lanes 0-15) ----
        if (wv == 0){
            float sm = red64(e0c + e1c);
            float sq = red64(e0c*e0c + e1c*e1c);
            float mu  = sm * (1.f/128.f);
            float var = sq * (1.f/128.f) - mu*mu;
            float inv = 1.f / sqrtf(var + 1e-5f);
            s_ci[lane]      = (e0c - mu)*inv*rg0 + rlb0;
            s_ci[64 + lane] = (e1c - mu)*inv*rg1 + rlb1;
        }
        if (wv == 1 && lane < NCL){
            float sp = s_spreads[lane], ma = s_masses[lane];
            float prec = 1.f/(sp + FEPS);
            float sc = ma + logf(prec + FEPS);
            float mx = max16(sc);
            float ex = expf(sc - mx);
            float smn = red16(ex);
            float al = ex / smn;
            s_alpha[lane] = al;
            float u = red16(al * sp);
            float mmx = max16(ma);
            float es = red16(expf(ma - mmx));
            float en = mmx + logf(es);
            float ent = -red16(al * logf(fmaxf(al, 1e-8f)));
            if (lane == 0){ s_ci[256] = u; s_ci[258] = en; s_ci[259] = ent; }
        }
        __syncthreads();  // B1

        // ---- phase 2b: core (tid<128) ----
        if (tid < HD){
            float acc = 0.f;
            #pragma unroll
            for (int c = 0; c < NCL; ++c) acc += s_alpha[c] * s_centers[c][tid];
            s_ci[128 + tid] = acc;
        }
        __syncthreads();  // B2

        // ---- diversity (wv0) concurrent with w1 partial (all 1024) ----
        if (wv == 0){
            int c = lane >> 2, p = lane & 3;
            float acc = 0.f;
            #pragma unroll 8
            for (int hh = p*32; hh < p*32 + 32; ++hh){
                float d = s_centers[c][hh] - s_ci[128 + hh];
                acc += d*d;
            }
            acc += __shfl_xor(acc, 1, 4); acc += __shfl_xor(acc, 2, 4);
            float v = ((lane & 3) == 0) ? s_alpha[c]*acc*(1.f/128.f) : 0.f;
            v = red64(v);
            if (lane == 0) s_ci[257] = v;   // k=257 skipped below, patched in final
        }
        // ---- phase 3 partial: ci @ w1 (LDS), 32 parts x 9, xor-32 in-wave ----
        {
            float a0=0.f,a1=0.f,a2=0.f,a3=0.f;
            #pragma unroll
            for (int u = 0; u < 9; ++u){
                int k = k0w1 + u;
                int kc = (k < 260) ? k : 0;                 // LDS read in-bounds
                float cv = (k == 257 || k >= 260) ? 0.f : s_ci[k];
                float4 w4 = *(const float4*)&s_w1[kc][jj];  // contiguous, conflict-free
                FMA4(cv, w4)
            }
            XOR4W(32)                                        // combine parts 2w,2w+1
            if (lane < 32) *(float4*)&s_red16[wv][jj] = make_float4(a0,a1,a2,a3);
        }
        __syncthreads();  // B3

        // ---- phase 3 final ----
        if (tid < HD){
            float acc = rb1 + rw257 * s_ci[257];
            #pragma unroll
            for (int p = 0; p < 16; ++p) acc += s_red16[p][tid];
            s_ctrl1[tid] = tanhf(acc);
        }
        __syncthreads();  // B4

        // ---- phase 4 partial: ctrl1 @ w2, 32 parts x 4, xor-32 ----
        {
            float a0=0.f,a1=0.f,a2=0.f,a3=0.f;
            #pragma unroll
            for (int u = 0; u < 4; ++u){
                int k = k0w2 + u;
                float4 w4 = *(const float4*)(w2 + k*HD + jj);  // coalesced
                float cl = s_ctrl1[k];
                FMA4(cl, w4)
            }
            XOR4W(32)
            if (lane < 32) *(float4*)&s_red16[wv][jj] = make_float4(a0,a1,a2,a3);
        }
        __syncthreads();  // B5

        // ---- phase 4 final ----
        if (tid < HD){
            float acc = rb2;
            #pragma unroll
            for (int p = 0; p < 16; ++p) acc += s_red16[p][tid];
            s_ctrl[tid] = tanhf(acc);
        }
        __syncthreads();  // B6

        // ---- att partial (tid<256, R6) + heads (waves 4-7, R6); waves 8-15 idle ----
        if (tid < 256){
            float a0=0.f,a1=0.f,a2=0.f,a3=0.f;
            #pragma unroll 8
            for (int u = 0; u < 16; ++u){
                int k = k0a + u;
                float4 w4 = *(const float4*)(att_w + k*HD + jj);
                float cl = s_ctrl[k];
                FMA4(cl, w4)
            }
            *(float4*)&s_red16[parta][jj] = make_float4(a0,a1,a2,a3);
        } else if (wv >= 4 && wv < 8){
            float4 acc = make_float4(0.f,0.f,0.f,0.f);
            #pragma unroll
            for (int u = 0; u < 8; ++u){
                int k = k0h + u;
                float4 hT = *(const float4*)(hwp + k*NCL + c4i*4);
                float cl = s_ctrl[k];
                acc.x = fmaf(cl, hT.x, acc.x);
                acc.y = fmaf(cl, hT.y, acc.y);
                acc.z = fmaf(cl, hT.z, acc.z);
                acc.w = fmaf(cl, hT.w, acc.w);
            }
            #pragma unroll
            for (int m = 4; m <= 32; m <<= 1){
                acc.x += __shfl_xor(acc.x, m, 64);
                acc.y += __shfl_xor(acc.y, m, 64);
                acc.z += __shfl_xor(acc.z, m, 64);
                acc.w += __shfl_xor(acc.w, m, 64);
            }
            if (lane < 4) *(float4*)&s_hred[wv-4][lane*4] = acc;
        }
        __syncthreads();  // B7

        // ---- finals: att sum (tid<128) / heads (wv2) / nov+relax (wv3) ----
        if (tid < HD){
            float acc = ratt;
            #pragma unroll
            for (int p = 0; p < 8; ++p) acc += s_red16[p][tid];
            s_att[tid] = acc;
        } else if (wv == 2 && lane < NCL){
            int c = lane;
            float g    = sigm(s_hred[0][c] + rgb) * valid;
            float araw = s_hred[1][c] + rab;
            float mx = max16(araw);
            float ex = expf(araw - mx);
            float smn = red16(ex);
            s_ss[c]    = g * (ex / smn);
            s_cands[c] = softplusf(s_hred[2][c] + rcb) + FEPS;
            s_mdl[c]   = tanhf(s_hred[3][c] + rmb);
        } else if (wv == 3){
            float c0 = s_ctrl[lane], c1v = s_ctrl[64 + lane];
            float np = red64(c0*rnw0 + c1v*rnw1);
            float rp = red64(c0*rrw0 + c1v*rrw1);
            if (lane == 0){
                s_scal[0] = sigm(np + rnb) * valid;
                s_scal[1] = sigm(rp + rrb) * valid;
            }
        }
        __syncthreads();  // B8

        // ---- phase 7: cc_w stream, contiguous k-halves, xor-1 combine ----
        {
            float a0=0.f,a1=0.f,a2=0.f,a3=0.f;
            const int kb = kh7 * 64;
            #pragma unroll 16
            for (int i = 0; i < 64; ++i){
                int k = kb + i;
                float cl = s_ctrl[k];
                float4 w4 = *(const float4*)(wq7 + ((size_t)k << 11));
                FMA4(cl, w4)
            }
            a0 += __shfl_xor(a0,1); a1 += __shfl_xor(a1,1);
            a2 += __shfl_xor(a2,1); a3 += __shfl_xor(a3,1);
            if (kh7 == 0){
                float ssc = s_ss[c7];
                float nv  = s_scal[0];
                float4 av = *(const float4*)&s_att[h7];
                float4* cp = (float4*)&s_centers[c7][h7];
                float4 ov = *cp;
                float x0 = ov.x + ssc*((a0 + ccb4.x) - ov.x); x0 = fmaf(0.1f*nv, av.x - x0, x0);
                float x1 = ov.y + ssc*((a1 + ccb4.y) - ov.y); x1 = fmaf(0.1f*nv, av.y - x1, x1);
                float x2 = ov.z + ssc*((a2 + ccb4.z) - ov.z); x2 = fmaf(0.1f*nv, av.z - x2, x2);
                float x3 = ov.w + ssc*((a3 + ccb4.w) - ov.w); x3 = fmaf(0.1f*nv, av.w - x3, x3);
                *cp = make_float4(x0, x1, x2, x3);
            }
        }
        if (tid < NCL){
            float ssc = s_ss[tid];
            s_spreads[tid] += ssc * (s_cands[tid] - s_spreads[tid]);
            s_masses[tid]  += ssc * s_mdl[tid];
        }
        __syncthreads();  // B9

        // ---- gram (R6-exact: 256 threads, no k-split) ----
        if (tid < 256){
            int gi = tid >> 4, gj = tid & 15;
            const float4* ri = (const float4*)&s_centers[gi][0];
            const float4* rj = (const float4*)&s_centers[gj][0];
            float acc = 0.f;
            #pragma unroll 8
            for (int h4 = 0; h4 < 32; ++h4){
                float4 a = ri[h4], b = rj[h4];
                acc = fmaf(a.x,b.x,fmaf(a.y,b.y,fmaf(a.z,b.z,fmaf(a.w,b.w,acc))));
            }
            s_gram[gi][gj] = acc;
        }
        __syncthreads();  // B10

        // ---- mixing softmax + mixed spreads/masses (R6-exact) ----
        if (tid < 256){
            int i = tid >> 4, jx = tid & 15;
            float g  = s_gram[i][jx];
            float d2 = fmaxf(s_gram[i][i] + s_gram[jx][jx] - 2.f*g, 0.f);
            float scale = s_spreads[i] + s_spreads[jx] + FEPS;
            float cmp = -d2/scale + s_masses[jx];
            float mx = max16(cmp);
            float ex = expf(cmp - mx);
            float smn = red16(ex);
            float mix = ex / smn;
            s_mix[i][jx] = mix;
            float msp = red16(mix * s_spreads[jx]);
            float mma = red16(mix * s_masses[jx]);
            if (jx == 0){ s_ms[i] = msp; s_mm[i] = mma; }
        }
        __syncthreads();  // B11

        // ---- merged: mixed centers + relax blend (tid<512, R6-exact) + shrink ----
        if (tid < 512){
            int i = tid & 15, hh = (tid >> 4)*4;
            float a0=0.f,a1=0.f,a2=0.f,a3=0.f;
            #pragma unroll
            for (int jc = 0; jc < NCL; ++jc){
                float m = s_mix[i][jc];
                float4 cv = *(const float4*)&s_centers[jc][hh];
                a0 = fmaf(m, cv.x, a0); a1 = fmaf(m, cv.y, a1);
                a2 = fmaf(m, cv.z, a2); a3 = fmaf(m, cv.w, a3);
            }
            float rx = s_scal[1];
            float4* cp2 = (float4*)&s_centers[i][hh];
            float4 ov = *cp2;
            ov.x = (1.f - rx)*ov.x + rx*a0;
            ov.y = (1.f - rx)*ov.y + rx*a1;
            ov.z = (1.f - rx)*ov.z + rx*a2;
            ov.w = (1.f - rx)*ov.w + rx*a3;
            *cp2 = ov;
        }
        if (tid < NCL){
            float rx = s_scal[1];
            float sp = (1.f - rx)*s_spreads[tid] + rx*s_ms[tid];
            float ma = (1.f - rx)*s_masses[tid]  + rx*s_mm[tid];
            float prec = 1.f/(sp + FEPS);
            float sc = ma + logf(prec + FEPS);
            float mx = max16(sc);
            float ex = expf(sc - mx);
            float smn = red16(ex);
            float ca = ex / smn;
            s_spreads[tid] = sp*(1.f - 0.05f*ca*valid) + FEPS;
            s_masses[tid]  = ma;
        }
        e0c = e0n; e1c = e1n;
        __syncthreads();  // B12
    }

    // ================= epilogue =================
    if (tid < NCL){
        float sp = s_spreads[tid], ma = s_masses[tid];
        float prec = 1.f/(sp + FEPS);
        float sc = ma + logf(prec + FEPS);
        float mx = max16(sc);
        float ex = expf(sc - mx);
        float smn = red16(ex);
        float al = ex / smn;
        s_alpha[tid] = al;
        float u = red16(al * sp);
        float mmx = max16(ma);
        float es = red16(expf(ma - mmx));
        float en = mmx + logf(es);
        float ent = -red16(al * logf(fmaxf(al, 1e-8f)));
        if (tid == 0){ s_ci[256] = u; s_ci[258] = en; s_ci[259] = ent; }
    }
    __syncthreads();
    if (tid < HD){
        float acc = 0.f;
        #pragma unroll
        for (int c = 0; c < NCL; ++c) acc += s_alpha[c] * s_centers[c][tid];
        s_ci[tid] = acc;   // core -> feats[0:128]
    }
    __syncthreads();
    if (wv == 0){
        int c = lane >> 2, p = lane & 3;
        float acc = 0.f;
        #pragma unroll 8
        for (int hh = p*32; hh < p*32 + 32; ++hh){
            float d = s_centers[c][hh] - s_ci[hh];
            acc += d*d;
        }
        acc += __shfl_xor(acc, 1, 4); acc += __shfl_xor(acc, 2, 4);
        float v = ((lane & 3) == 0) ? s_alpha[c]*acc*(1.f/128.f) : 0.f;
        v = red64(v);
        if (lane == 0) s_ci[257] = v;
    }
    if (wv == 1 && lane == 0){
        int best = 0; float bv = s_alpha[0];
        for (int c = 1; c < NCL; ++c){ if (s_alpha[c] > bv){ bv = s_alpha[c]; best = c; } }
        s_ibest = best;
    }
    __syncthreads();
    if (tid < HD) s_ci[128 + tid] = s_centers[s_ibest][tid];   // strongest
    __syncthreads();
    // classifier layer 1 (one-time; tid<512 covers k 0..259)
    if (tid < 512){
        int j = tid & 127, p4 = tid >> 7;
        int k0 = p4*65;
        float acc = 0.f;
        for (int k = k0; k < k0 + 65; ++k) acc += s_ci[k] * cw1[k*HD + j];
        s_red16[p4][j] = acc;
    }
    __syncthreads();
    if (tid < HD){
        float x = cb1[tid] + s_red16[0][tid] + s_red16[1][tid] + s_red16[2][tid] + s_red16[3][tid];
        s_ctrl1[tid] = 0.5f*x*(1.f + erff(x*0.70710678118654752f));  // exact gelu
    }
    __syncthreads();
    // classifier layer 2 -> out
    if (tid < 64){
        int n = tid >> 3, p = tid & 7;
        float acc = 0.f;
        #pragma unroll
        for (int kk = 0; kk < 16; ++kk){ int jx = p*16 + kk; acc += s_ctrl1[jx] * cw2[jx*NOUT + n]; }
        acc += __shfl_xor(acc, 1, 8); acc += __shfl_xor(acc, 2, 8); acc += __shfl_xor(acc, 4, 8);
        if (p == 0) out[bidx*NOUT + n] = acc + cb2[n];
    }
}

extern "C" void kernel_launch(void* const* d_in, const int* in_sizes, int n_in,
                              void* d_out, int out_size, void* d_ws, size_t ws_size,
                              hipStream_t stream) {
    const int*   tokens   = (const int*)  d_in[0];
    const float* emb      = (const float*)d_in[1];
    const float* ln_g     = (const float*)d_in[2];
    const float* ln_b     = (const float*)d_in[3];
    const float* ctrl_w1  = (const float*)d_in[4];
    const float* ctrl_b1  = (const float*)d_in[5];
    const float* ctrl_w2  = (const float*)d_in[6];
    const float* ctrl_b2  = (const float*)d_in[7];
    const float* gate_w   = (const float*)d_in[8];
    const float* gate_b   = (const float*)d_in[9];
    const float* assign_w = (const float*)d_in[10];
    const float* assign_b = (const float*)d_in[11];
    const float* nov_w    = (const float*)d_in[12];
    const float* nov_b    = (const float*)d_in[13];
    const float* relax_w  = (const float*)d_in[14];
    const float* relax_b  = (const float*)d_in[15];
    const float* cc_w     = (const float*)d_in[16];
    const float* cc_b     = (const float*)d_in[17];
    const float* cs_w     = (const float*)d_in[18];
    const float* cs_b     = (const float*)d_in[19];
    const float* md_w     = (const float*)d_in[20];
    const float* md_b     = (const float*)d_in[21];
    const float* att_w    = (const float*)d_in[22];
    const float* att_b    = (const float*)d_in[23];
    const float* cls_w1   = (const float*)d_in[24];
    const float* cls_b1   = (const float*)d_in[25];
    const float* cls_w2   = (const float*)d_in[26];
    const float* cls_b2   = (const float*)d_in[27];
    float* out = (float*)d_out;

    hipLaunchKernelGGL(cfrm_kernel, dim3(NB), dim3(1024), 0, stream,
                       tokens, emb, ln_g, ln_b,
                       ctrl_w1, ctrl_b1, ctrl_w2, ctrl_b2,
                       gate_w, gate_b, assign_w, assign_b,
                       nov_w, nov_b, relax_w, relax_b,
                       cc_w, cc_b, cs_w, cs_b, md_w, md_b,
                       att_w, att_b, cls_w1, cls_b1, cls_w2, cls_b2,
                       out);
}

// Round 11
// 8667.207 us; speedup vs baseline: 1.6005x; 1.4625x over previous
//
#include <hip/hip_runtime.h>
#include <hip/hip_fp16.h>
#include <math.h>

#define NB   128   // batch
#define SEQ  512   // sequence length
#define HD   128   // hidden
#define NCL  16    // clusters C
#define NOUT 8     // classes
#define CIP  272   // ci padded (260 real)
#define FEPS 1e-4f
#define HP   132   // padded row stride for centers

// NOTE: macro param must NOT be named 'w'/'x'/'y'/'z' (member-access collision).
#define FMA4(cc, W4) { a0 = fmaf((cc),(W4).x,a0); a1 = fmaf((cc),(W4).y,a1); a2 = fmaf((cc),(W4).z,a2); a3 = fmaf((cc),(W4).w,a3); }

__device__ __forceinline__ float red16(float v){
    v += __shfl_xor(v, 1, 16); v += __shfl_xor(v, 2, 16);
    v += __shfl_xor(v, 4, 16); v += __shfl_xor(v, 8, 16);
    return v;
}
__device__ __forceinline__ float max16(float v){
    v = fmaxf(v, __shfl_xor(v, 1, 16)); v = fmaxf(v, __shfl_xor(v, 2, 16));
    v = fmaxf(v, __shfl_xor(v, 4, 16)); v = fmaxf(v, __shfl_xor(v, 8, 16));
    return v;
}
__device__ __forceinline__ float red64(float v){
    v += __shfl_xor(v, 1, 64); v += __shfl_xor(v, 2, 64); v += __shfl_xor(v, 4, 64);
    v += __shfl_xor(v, 8, 64); v += __shfl_xor(v,16, 64); v += __shfl_xor(v,32, 64);
    return v;
}
__device__ __forceinline__ float sigm(float x){ return 1.f/(1.f + expf(-x)); }
__device__ __forceinline__ float softplusf(float x){ return log1pf(expf(-fabsf(x))) + fmaxf(x, 0.f); }

// prep: pack cc_w f32 -> fp16 k-pair interleaved: pack[k2][j][m] with m = k&1.
// One 16B load in the main kernel = 4 adjacent j x 2 k. Runs every launch.
__global__ __launch_bounds__(256)
void convert_ccw(const float* __restrict__ src, __half* __restrict__ dst){
    int i = blockIdx.x*256 + threadIdx.x;   // 32768 threads
    int k2 = i >> 9;                         // 0..63
    int jg = i & 511;                        // j0 = jg*4
    float4 va = ((const float4*)(src + (size_t)(2*k2)*2048))[jg];
    float4 vb = ((const float4*)(src + (size_t)(2*k2+1)*2048))[jg];
    __half2 h0 = __floats2half2_rn(va.x, vb.x);
    __half2 h1 = __floats2half2_rn(va.y, vb.y);
    __half2 h2 = __floats2half2_rn(va.z, vb.z);
    __half2 h3 = __floats2half2_rn(va.w, vb.w);
    __half2* o = (__half2*)dst + (size_t)k2*2048 + jg*4;
    o[0]=h0; o[1]=h1; o[2]=h2; o[3]=h3;
}

// R6 base (best measured: 11.16ms). This round: cc stream packed-fp16 (64
// contiguous 16B loads/thread, 4 latency batches vs 8) and HOISTED into the
// att/heads region (only needs s_ctrl); old stream region becomes a tiny RMW.
// Operating point (R8/R10 refuted 1024t): 512 threads, 128 VGPR, 2 waves/SIMD.
// R4/R5: no persistent per-thread arrays. R9: keep wave reads contiguous.
template<int USE16>
__global__ __launch_bounds__(512)
void cfrm_kernel(const int*  __restrict__ tokens,
                 const float* __restrict__ emb,
                 const float* __restrict__ ln_g, const float* __restrict__ ln_b,
                 const float* __restrict__ w1,   const float* __restrict__ b1,
                 const float* __restrict__ w2,   const float* __restrict__ b2,
                 const float* __restrict__ gate_w, const float* __restrict__ gate_b,
                 const float* __restrict__ assign_w, const float* __restrict__ assign_b,
                 const float* __restrict__ nov_w, const float* __restrict__ nov_b,
                 const float* __restrict__ relax_w, const float* __restrict__ relax_b,
                 const float* __restrict__ cc_w, const float* __restrict__ cc_b,
                 const __half* __restrict__ ccw_h,
                 const float* __restrict__ cs_w, const float* __restrict__ cs_b,
                 const float* __restrict__ md_w, const float* __restrict__ md_b,
                 const float* __restrict__ att_w, const float* __restrict__ att_b,
                 const float* __restrict__ cw1,  const float* __restrict__ cb1,
                 const float* __restrict__ cw2,  const float* __restrict__ cb2,
                 float* __restrict__ out)
{
    const int bidx = blockIdx.x;
    const int tid  = threadIdx.x;
    const int lane = tid & 63;
    const int wv   = tid >> 6;

    // ---- LDS (~157 KiB; 1 block/CU) ----
    __shared__ __align__(16) float s_w1[260][HD];   // 133.1 KB, staged once
    __shared__ __align__(16) float s_centers[NCL][HP];
    __shared__ __align__(16) float s_ci[CIP];
    __shared__ __align__(16) float s_ctrl1[HD];
    __shared__ __align__(16) float s_ctrl[HD];
    __shared__ __align__(16) float s_red16[16][HD];
    __shared__ __align__(16) float s_hred[4][NCL];
    __shared__ __align__(16) float s_att[HD];
    __shared__ __align__(16) float s_gram[NCL][NCL+1];
    __shared__ __align__(16) float s_mix[NCL][NCL+1];
    __shared__ float s_alpha[NCL], s_spreads[NCL], s_masses[NCL];
    __shared__ float s_ss[NCL], s_cands[NCL], s_mdl[NCL];
    __shared__ float s_ms[NCL], s_mm[NCL];
    __shared__ float s_scal[2];
    __shared__ int   s_ibest;
    __shared__ int   s_tok[SEQ];

    // ---- stage w1 -> LDS (one-time) ----
    {
        const float4* w1f4 = (const float4*)w1;
        float4* s_w1f4 = (float4*)s_w1;
        for (int idx = tid; idx < 260*32; idx += 512) s_w1f4[idx] = w1f4[idx];
    }

    // ---- init state / token preload ----
    for (int i = tid; i < NCL*HP; i += 512) ((float*)s_centers)[i] = 0.f;
    if (tid >= 260 && tid < CIP) s_ci[tid] = 0.f;
    if (tid < NCL){ s_spreads[tid] = 1.f; s_masses[tid] = 0.f; }
    s_tok[tid] = tokens[bidx*SEQ + tid];

    // ---- per-thread constant preloads (scalars only) ----
    float rb1 = 0.f, rb2 = 0.f, ratt = 0.f, rw257 = 0.f;
    if (tid < HD){ rb1 = b1[tid]; rb2 = b2[tid]; ratt = att_b[tid]; rw257 = w1[257*HD + tid]; }
    float rg0=0.f, rg1=0.f, rlb0=0.f, rlb1=0.f;
    if (wv == 0){ rg0 = ln_g[lane]; rg1 = ln_g[64+lane]; rlb0 = ln_b[lane]; rlb1 = ln_b[64+lane]; }
    float rgb=0.f, rab=0.f, rcb=0.f, rmb=0.f;
    if (wv == 2 && lane < NCL){ rgb = gate_b[lane]; rab = assign_b[lane]; rcb = cs_b[lane]; rmb = md_b[lane]; }
    float rnw0=0.f, rnw1=0.f, rrw0=0.f, rrw1=0.f, rnb=0.f, rrb=0.f;
    if (wv == 3){ rnw0 = nov_w[lane]; rnw1 = nov_w[64+lane]; rrw0 = relax_w[lane]; rrw1 = relax_w[64+lane];
                  rnb = nov_b[0]; rrb = relax_b[0]; }

    // phase-7 per-thread geometry
    const int j0 = tid*4, ci_c = j0 >> 7, ci_h = j0 & 127;
    const float4 ccb4 = *(const float4*)(cc_b + j0);
    const float* wp = cc_w + j0;
    const __half2* pk = (const __half2*)ccw_h + tid*4;   // row k2 = 2048 half2

    // matvec mapping (R6): 32 j-groups x 16 k-parts
    const int jj   = (tid & 31)*4;
    const int part = tid >> 5;          // 0..15
    const int k0w1 = part*17;
    const int k0w2 = part*8;

    // att / heads geometry (R6)
    const int parta = (tid >> 5) & 7;
    const int k0a   = parta*16;
    const float* hwp = gate_w; int c4i = 0, k0h = 0;
    if (wv >= 4){
        int head = wv - 4;
        hwp = (head==0) ? gate_w : (head==1) ? assign_w : (head==2) ? cs_w : md_w;
        c4i = lane & 3; k0h = (lane >> 2)*8;
    }

    __syncthreads();

    // emb prefetch for s=0
    float e0c = 0.f, e1c = 0.f;
    if (wv == 0){
        int t0 = s_tok[0];
        e0c = emb[(size_t)t0*HD + lane];
        e1c = emb[(size_t)t0*HD + 64 + lane];
    }

    for (int s = 0; s < SEQ; ++s){
        const int tok = s_tok[s];
        const float valid = (tok != 0) ? 1.f : 0.f;

        float e0n = 0.f, e1n = 0.f;
        if (wv == 0 && s + 1 < SEQ){
            int tn = s_tok[s+1];
            e0n = emb[(size_t)tn*HD + lane];
            e1n = emb[(size_t)tn*HD + 64 + lane];
        }

        // ---- phase 1: LayerNorm (wv0) | summarize (wv1 lanes 0-15) ----
        if (wv == 0){
            float sm = red64(e0c + e1c);
            float sq = red64(e0c*e0c + e1c*e1c);
            float mu  = sm * (1.f/128.f);
            float var = sq * (1.f/128.f) - mu*mu;
            float inv = 1.f / sqrtf(var + 1e-5f);
            s_ci[lane]      = (e0c - mu)*inv*rg0 + rlb0;
            s_ci[64 + lane] = (e1c - mu)*inv*rg1 + rlb1;
        }
        if (wv == 1 && lane < NCL){
            float sp = s_spreads[lane], ma = s_masses[lane];
            float prec = 1.f/(sp + FEPS);
            float sc = ma + logf(prec + FEPS);
            float mx = max16(sc);
            float ex = expf(sc - mx);
            float smn = red16(ex);
            float al = ex / smn;
            s_alpha[lane] = al;
            float u = red16(al * sp);
            float mmx = max16(ma);
            float es = red16(expf(ma - mmx));
            float en = mmx + logf(es);
            float ent = -red16(al * logf(fmaxf(al, 1e-8f)));
            if (lane == 0){ s_ci[256] = u; s_ci[258] = en; s_ci[259] = ent; }
        }
        __syncthreads();  // B1

        // ---- phase 2b: core ----
        if (tid < HD){
            float acc = 0.f;
            #pragma unroll
            for (int c = 0; c < NCL; ++c) acc += s_alpha[c] * s_centers[c][tid];
            s_ci[128 + tid] = acc;
        }
        __syncthreads();  // B2

        // ---- diversity (wv0) concurrent with w1 partial ----
        if (wv == 0){
            int c = lane >> 2, p = lane & 3;
            float acc = 0.f;
            #pragma unroll 8
            for (int hh = p*32; hh < p*32 + 32; ++hh){
                float d = s_centers[c][hh] - s_ci[128 + hh];
                acc += d*d;
            }
            acc += __shfl_xor(acc, 1, 4); acc += __shfl_xor(acc, 2, 4);
            float v = ((lane & 3) == 0) ? s_alpha[c]*acc*(1.f/128.f) : 0.f;
            v = red64(v);
            if (lane == 0) s_ci[257] = v;   // k=257 skipped below, patched in final
        }
        // ---- phase 3 partial: ci @ w1 (LDS) ----
        {
            float a0=0.f,a1=0.f,a2=0.f,a3=0.f;
            #pragma unroll
            for (int u = 0; u < 17; ++u){
                int k = k0w1 + u;
                int kc = (k < 260) ? k : 0;
                float cv = (k == 257) ? 0.f : s_ci[k];      // s_ci[260..271]==0
                float4 w4 = *(const float4*)&s_w1[kc][jj];
                FMA4(cv, w4)
            }
            *(float4*)&s_red16[part][jj] = make_float4(a0,a1,a2,a3);
        }
        __syncthreads();  // B3

        // ---- phase 3 final ----
        if (tid < HD){
            float acc = rb1 + rw257 * s_ci[257];
            #pragma unroll
            for (int p = 0; p < 16; ++p) acc += s_red16[p][tid];
            s_ctrl1[tid] = tanhf(acc);
        }
        __syncthreads();  // B4

        // ---- phase 4 partial: ctrl1 @ w2 ----
        {
            float a0=0.f,a1=0.f,a2=0.f,a3=0.f;
            #pragma unroll
            for (int u = 0; u < 8; ++u){
                int k = k0w2 + u;
                float4 w4 = *(const float4*)(w2 + k*HD + jj);
                float cl = s_ctrl1[k];
                FMA4(cl, w4)
            }
            *(float4*)&s_red16[part][jj] = make_float4(a0,a1,a2,a3);
        }
        __syncthreads();  // B5

        // ---- phase 4 final ----
        if (tid < HD){
            float acc = rb2;
            #pragma unroll
            for (int p = 0; p < 16; ++p) acc += s_red16[p][tid];
            s_ctrl[tid] = tanhf(acc);
        }
        __syncthreads();  // B6

        // ==== merged region: cc stream (all threads; needs only s_ctrl) +
        //      att partial (tid<256) + heads (waves 4-7) ====
        float a0=0.f, a1=0.f, a2=0.f, a3=0.f;   // cc accumulators, live to B8+
        if constexpr (USE16){
            #pragma unroll 8
            for (int k2 = 0; k2 < 64; ++k2){
                float c0 = s_ctrl[2*k2], c1 = s_ctrl[2*k2+1];
                float4 raw = *(const float4*)(pk + (k2 << 11));
                const __half2* h2p = (const __half2*)&raw;
                float2 f0 = __half22float2(h2p[0]);
                float2 f1 = __half22float2(h2p[1]);
                float2 f2 = __half22float2(h2p[2]);
                float2 f3 = __half22float2(h2p[3]);
                a0 = fmaf(c0,f0.x,fmaf(c1,f0.y,a0));
                a1 = fmaf(c0,f1.x,fmaf(c1,f1.y,a1));
                a2 = fmaf(c0,f2.x,fmaf(c1,f2.y,a2));
                a3 = fmaf(c0,f3.x,fmaf(c1,f3.y,a3));
            }
        } else {
            #pragma unroll 16
            for (int k = 0; k < HD; ++k){
                float cl = s_ctrl[k];
                float4 w4 = *(const float4*)(wp + ((size_t)k << 11));
                FMA4(cl, w4)
            }
        }
        if (tid < 256){
            float t0=0.f,t1=0.f,t2=0.f,t3=0.f;
            #pragma unroll 8
            for (int u = 0; u < 16; ++u){
                int k = k0a + u;
                float4 w4 = *(const float4*)(att_w + k*HD + jj);
                float cl = s_ctrl[k];
                t0 = fmaf(cl, w4.x, t0); t1 = fmaf(cl, w4.y, t1);
                t2 = fmaf(cl, w4.z, t2); t3 = fmaf(cl, w4.w, t3);
            }
            *(float4*)&s_red16[parta][jj] = make_float4(t0,t1,t2,t3);
        } else {
            float4 acc = make_float4(0.f,0.f,0.f,0.f);
            #pragma unroll
            for (int u = 0; u < 8; ++u){
                int k = k0h + u;
                float4 hT = *(const float4*)(hwp + k*NCL + c4i*4);
                float cl = s_ctrl[k];
                acc.x = fmaf(cl, hT.x, acc.x);
                acc.y = fmaf(cl, hT.y, acc.y);
                acc.z = fmaf(cl, hT.z, acc.z);
                acc.w = fmaf(cl, hT.w, acc.w);
            }
            #pragma unroll
            for (int m = 4; m <= 32; m <<= 1){
                acc.x += __shfl_xor(acc.x, m, 64);
                acc.y += __shfl_xor(acc.y, m, 64);
                acc.z += __shfl_xor(acc.z, m, 64);
                acc.w += __shfl_xor(acc.w, m, 64);
            }
            if (lane < 4) *(float4*)&s_hred[wv-4][lane*4] = acc;
        }
        __syncthreads();  // B7

        // ---- finals: att sum / head activations / novelty+relax ----
        if (tid < HD){
            float acc = ratt;
            #pragma unroll
            for (int p = 0; p < 8; ++p) acc += s_red16[p][tid];
            s_att[tid] = acc;
        } else if (wv == 2 && lane < NCL){
            int c = lane;
            float g    = sigm(s_hred[0][c] + rgb) * valid;
            float araw = s_hred[1][c] + rab;
            float mx = max16(araw);
            float ex = expf(araw - mx);
            float smn = red16(ex);
            s_ss[c]    = g * (ex / smn);
            s_cands[c] = softplusf(s_hred[2][c] + rcb) + FEPS;
            s_mdl[c]   = tanhf(s_hred[3][c] + rmb);
        } else if (wv == 3){
            float c0 = s_ctrl[lane], c1v = s_ctrl[64 + lane];
            float np = red64(c0*rnw0 + c1v*rnw1);
            float rp = red64(c0*rrw0 + c1v*rrw1);
            if (lane == 0){
                s_scal[0] = sigm(np + rnb) * valid;
                s_scal[1] = sigm(rp + rrb) * valid;
            }
        }
        __syncthreads();  // B8

        // ---- tiny region: apply center update (accs from merged region) ----
        {
            float ssc = s_ss[ci_c];
            float nv  = s_scal[0];
            float4 av = *(const float4*)&s_att[ci_h];
            float4* cp = (float4*)&s_centers[ci_c][ci_h];
            float4 ov = *cp;
            float x0 = ov.x + ssc*((a0 + ccb4.x) - ov.x); x0 = fmaf(0.1f*nv, av.x - x0, x0);
            float x1 = ov.y + ssc*((a1 + ccb4.y) - ov.y); x1 = fmaf(0.1f*nv, av.y - x1, x1);
            float x2 = ov.z + ssc*((a2 + ccb4.z) - ov.z); x2 = fmaf(0.1f*nv, av.z - x2, x2);
            float x3 = ov.w + ssc*((a3 + ccb4.w) - ov.w); x3 = fmaf(0.1f*nv, av.w - x3, x3);
            *cp = make_float4(x0, x1, x2, x3);
        }
        if (tid < NCL){
            float ssc = s_ss[tid];
            s_spreads[tid] += ssc * (s_cands[tid] - s_spreads[tid]);
            s_masses[tid]  += ssc * s_mdl[tid];
        }
        __syncthreads();  // B9

        // ---- gram ----
        if (tid < 256){
            int gi = tid >> 4, gj = tid & 15;
            const float4* ri = (const float4*)&s_centers[gi][0];
            const float4* rj = (const float4*)&s_centers[gj][0];
            float acc = 0.f;
            #pragma unroll 8
            for (int h4 = 0; h4 < 32; ++h4){
                float4 a = ri[h4], b = rj[h4];
                acc = fmaf(a.x,b.x,fmaf(a.y,b.y,fmaf(a.z,b.z,fmaf(a.w,b.w,acc))));
            }
            s_gram[gi][gj] = acc;
        }
        __syncthreads();  // B10

        // ---- mixing softmax + mixed spreads/masses ----
        if (tid < 256){
            int i = tid >> 4, jx = tid & 15;
            float g  = s_gram[i][jx];
            float d2 = fmaxf(s_gram[i][i] + s_gram[jx][jx] - 2.f*g, 0.f);
            float scale = s_spreads[i] + s_spreads[jx] + FEPS;
            float cmp = -d2/scale + s_masses[jx];
            float mx = max16(cmp);
            float ex = expf(cmp - mx);
            float smn = red16(ex);
            float mix = ex / smn;
            s_mix[i][jx] = mix;
            float msp = red16(mix * s_spreads[jx]);
            float mma = red16(mix * s_masses[jx]);
            if (jx == 0){ s_ms[i] = msp; s_mm[i] = mma; }
        }
        __syncthreads();  // B11

        // ---- merged: mixed centers + relax blend + spread shrink ----
        {
            int i = tid & 15, hh = (tid >> 4)*4;
            float t0=0.f,t1=0.f,t2=0.f,t3=0.f;
            #pragma unroll
            for (int jc = 0; jc < NCL; ++jc){
                float m = s_mix[i][jc];
                float4 cv = *(const float4*)&s_centers[jc][hh];
                t0 = fmaf(m, cv.x, t0); t1 = fmaf(m, cv.y, t1);
                t2 = fmaf(m, cv.z, t2); t3 = fmaf(m, cv.w, t3);
            }
            float rx = s_scal[1];
            float4* cp2 = (float4*)&s_centers[i][hh];
            float4 ov = *cp2;
            ov.x = (1.f - rx)*ov.x + rx*t0;
            ov.y = (1.f - rx)*ov.y + rx*t1;
            ov.z = (1.f - rx)*ov.z + rx*t2;
            ov.w = (1.f - rx)*ov.w + rx*t3;
            *cp2 = ov;
        }
        if (tid < NCL){
            float rx = s_scal[1];
            float sp = (1.f - rx)*s_spreads[tid] + rx*s_ms[tid];
            float ma = (1.f - rx)*s_masses[tid]  + rx*s_mm[tid];
            float prec = 1.f/(sp + FEPS);
            float sc = ma + logf(prec + FEPS);
            float mx = max16(sc);
            float ex = expf(sc - mx);
            float smn = red16(ex);
            float ca = ex / smn;
            s_spreads[tid] = sp*(1.f - 0.05f*ca*valid) + FEPS;
            s_masses[tid]  = ma;
        }
        e0c = e0n; e1c = e1n;
        __syncthreads();  // B12
    }

    // ================= epilogue =================
    if (tid < NCL){
        float sp = s_spreads[tid], ma = s_masses[tid];
        float prec = 1.f/(sp + FEPS);
        float sc = ma + logf(prec + FEPS);
        float mx = max16(sc);
        float ex = expf(sc - mx);
        float smn = red16(ex);
        float al = ex / smn;
        s_alpha[tid] = al;
        float u = red16(al * sp);
        float mmx = max16(ma);
        float es = red16(expf(ma - mmx));
        float en = mmx + logf(es);
        float ent = -red16(al * logf(fmaxf(al, 1e-8f)));
        if (tid == 0){ s_ci[256] = u; s_ci[258] = en; s_ci[259] = ent; }
    }
    __syncthreads();
    if (tid < HD){
        float acc = 0.f;
        #pragma unroll
        for (int c = 0; c < NCL; ++c) acc += s_alpha[c] * s_centers[c][tid];
        s_ci[tid] = acc;   // core -> feats[0:128]
    }
    __syncthreads();
    if (wv == 0){
        int c = lane >> 2, p = lane & 3;
        float acc = 0.f;
        #pragma unroll 8
        for (int hh = p*32; hh < p*32 + 32; ++hh){
            float d = s_centers[c][hh] - s_ci[hh];
            acc += d*d;
        }
        acc += __shfl_xor(acc, 1, 4); acc += __shfl_xor(acc, 2, 4);
        float v = ((lane & 3) == 0) ? s_alpha[c]*acc*(1.f/128.f) : 0.f;
        v = red64(v);
        if (lane == 0) s_ci[257] = v;
    }
    if (wv == 1 && lane == 0){
        int best = 0; float bv = s_alpha[0];
        for (int c = 1; c < NCL; ++c){ if (s_alpha[c] > bv){ bv = s_alpha[c]; best = c; } }
        s_ibest = best;
    }
    __syncthreads();
    if (tid < HD) s_ci[128 + tid] = s_centers[s_ibest][tid];   // strongest
    __syncthreads();
    // classifier layer 1: gelu(feats @ cw1 + cb1)  (one-time)
    {
        int j = tid & 127, p4 = tid >> 7;
        int k0 = p4*65;
        float acc = 0.f;
        for (int k = k0; k < k0 + 65; ++k) acc += s_ci[k] * cw1[k*HD + j];
        s_red16[p4][j] = acc;
    }
    __syncthreads();
    if (tid < HD){
        float x = cb1[tid] + s_red16[0][tid] + s_red16[1][tid] + s_red16[2][tid] + s_red16[3][tid];
        s_ctrl1[tid] = 0.5f*x*(1.f + erff(x*0.70710678118654752f));  // exact gelu
    }
    __syncthreads();
    // classifier layer 2 -> out
    if (tid < 64){
        int n = tid >> 3, p = tid & 7;
        float acc = 0.f;
        #pragma unroll
        for (int kk = 0; kk < 16; ++kk){ int jx = p*16 + kk; acc += s_ctrl1[jx] * cw2[jx*NOUT + n]; }
        acc += __shfl_xor(acc, 1, 8); acc += __shfl_xor(acc, 2, 8); acc += __shfl_xor(acc, 4, 8);
        if (p == 0) out[bidx*NOUT + n] = acc + cb2[n];
    }
}

extern "C" void kernel_launch(void* const* d_in, const int* in_sizes, int n_in,
                              void* d_out, int out_size, void* d_ws, size_t ws_size,
                              hipStream_t stream) {
    const int*   tokens   = (const int*)  d_in[0];
    const float* emb      = (const float*)d_in[1];
    const float* ln_g     = (const float*)d_in[2];
    const float* ln_b     = (const float*)d_in[3];
    const float* ctrl_w1  = (const float*)d_in[4];
    const float* ctrl_b1  = (const float*)d_in[5];
    const float* ctrl_w2  = (const float*)d_in[6];
    const float* ctrl_b2  = (const float*)d_in[7];
    const float* gate_w   = (const float*)d_in[8];
    const float* gate_b   = (const float*)d_in[9];
    const float* assign_w = (const float*)d_in[10];
    const float* assign_b = (const float*)d_in[11];
    const float* nov_w    = (const float*)d_in[12];
    const float* nov_b    = (const float*)d_in[13];
    const float* relax_w  = (const float*)d_in[14];
    const float* relax_b  = (const float*)d_in[15];
    const float* cc_w     = (const float*)d_in[16];
    const float* cc_b     = (const float*)d_in[17];
    const float* cs_w     = (const float*)d_in[18];
    const float* cs_b     = (const float*)d_in[19];
    const float* md_w     = (const float*)d_in[20];
    const float* md_b     = (const float*)d_in[21];
    const float* att_w    = (const float*)d_in[22];
    const float* att_b    = (const float*)d_in[23];
    const float* cls_w1   = (const float*)d_in[24];
    const float* cls_b1   = (const float*)d_in[25];
    const float* cls_w2   = (const float*)d_in[26];
    const float* cls_b2   = (const float*)d_in[27];
    float* out = (float*)d_out;

    const size_t need = (size_t)2048 * 128 * sizeof(__half);   // 512 KB
    if (ws_size >= need){
        __half* ccw_h = (__half*)d_ws;
        hipLaunchKernelGGL(convert_ccw, dim3(128), dim3(256), 0, stream, cc_w, ccw_h);
        hipLaunchKernelGGL((cfrm_kernel<1>), dim3(NB), dim3(512), 0, stream,
                           tokens, emb, ln_g, ln_b,
                           ctrl_w1, ctrl_b1, ctrl_w2, ctrl_b2,
                           gate_w, gate_b, assign_w, assign_b,
                           nov_w, nov_b, relax_w, relax_b,
                           cc_w, cc_b, ccw_h, cs_w, cs_b, md_w, md_b,
                           att_w, att_b, cls_w1, cls_b1, cls_w2, cls_b2,
                           out);
    } else {
        hipLaunchKernelGGL((cfrm_kernel<0>), dim3(NB), dim3(512), 0, stream,
                           tokens, emb, ln_g, ln_b,
                           ctrl_w1, ctrl_b1, ctrl_w2, ctrl_b2,
                           gate_w, gate_b, assign_w, assign_b,
                           nov_w, nov_b, relax_w, relax_b,
                           cc_w, cc_b, (const __half*)nullptr, cs_w, cs_b, md_w, md_b,
                           att_w, att_b, cls_w1, cls_b1, cls_w2, cls_b2,
                           out);
    }
}